// Round 14
// baseline (387.151 us; speedup 1.0000x reference)
//
#include <hip/hip_runtime.h>
#include <math.h>

#define DA 64
#define EPSC 1e-8f

typedef short v8s __attribute__((ext_vector_type(8)));
typedef float v4f __attribute__((ext_vector_type(4)));
typedef unsigned short ushort_t;

// fast silu: v * rcp(1+exp(-v))
__device__ __forceinline__ float siluf(float v) {
  return v * __builtin_amdgcn_rcpf(1.0f + __expf(-v));
}
// fast tanh: 1 - 2*rcp(exp(2x)+1)
__device__ __forceinline__ float tanhfast(float x) {
  return 1.0f - 2.0f * __builtin_amdgcn_rcpf(__expf(2.0f * x) + 1.0f);
}

__device__ __forceinline__ unsigned short f2bfu(float f) {
  union { float f; unsigned u; } v; v.f = f;
  unsigned r = v.u + 0x7fffu + ((v.u >> 16) & 1u);
  return (unsigned short)(r >> 16);
}
__device__ __forceinline__ short f2bfs(float f) { return (short)f2bfu(f); }
__device__ __forceinline__ float bf2f(ushort_t s) {
  union { unsigned u; float f; } v; v.u = ((unsigned)s) << 16; return v.f;
}

#define MU0 0.60653065971263342f
#define DMU ((1.0f - 0.60653065971263342f) / 19.0f)
#define BETA ((float)(1.0 / (0.039346934028736658 * 0.039346934028736658)))

// ---------------------------------------------------------------------------
// fused: bf16 cast of h  +  degree count
// ---------------------------------------------------------------------------
__global__ __launch_bounds__(256) void cast_count(
    const float* __restrict__ hsrc, ushort_t* __restrict__ hb, int n4,
    const int* __restrict__ idx_i, int* __restrict__ deg, int E)
{
  const int stride = gridDim.x * blockDim.x;
  for (int i = blockIdx.x * blockDim.x + threadIdx.x; i < n4; i += stride) {
    const float4 fv = ((const float4*)hsrc)[i];
    ushort4 o;
    o.x = f2bfu(fv.x); o.y = f2bfu(fv.y); o.z = f2bfu(fv.z); o.w = f2bfu(fv.w);
    ((ushort4*)hb)[i] = o;
  }
  for (int e = blockIdx.x * blockDim.x + threadIdx.x; e < E; e += stride)
    atomicAdd(&deg[idx_i[e]], 1);
}

// ---------------------------------------------------------------------------
#define SCAN_B 64
#define SCAN_T (SCAN_B * 256)

__global__ __launch_bounds__(256) void deg_tsum(
    const int* __restrict__ deg, int* __restrict__ tsum, int N, int C)
{
  const int g = blockIdx.x * blockDim.x + threadIdx.x;
  const int lo = g * C;
  const int hi = (lo + C < N) ? (lo + C) : N;
  int s = 0;
  for (int i = lo; i < hi; ++i) s += deg[i];
  tsum[g] = s;
}

__global__ __launch_bounds__(256) void scan_tsum(int* __restrict__ tsum)
{
  __shared__ int ps[256];
  const int t = threadIdx.x;
  const int per = SCAN_T / 256;
  const int lo = t * per;
  int s = 0;
  for (int i = 0; i < per; ++i) s += tsum[lo + i];
  ps[t] = s;
  __syncthreads();
  if (t == 0) {
    int a = 0;
    for (int i = 0; i < 256; ++i) { const int v = ps[i]; ps[i] = a; a += v; }
  }
  __syncthreads();
  int acc = ps[t];
  for (int i = 0; i < per; ++i) {
    const int v = tsum[lo + i];
    tsum[lo + i] = acc;
    acc += v;
  }
}

__global__ __launch_bounds__(256) void write_csr(
    const int* __restrict__ deg, const int* __restrict__ tpre,
    int* __restrict__ rowstart, int* __restrict__ cursor, int N, int C)
{
  const int g = blockIdx.x * blockDim.x + threadIdx.x;
  const int lo = g * C;
  const int hi = (lo + C < N) ? (lo + C) : N;
  int acc = tpre[g];
  for (int i = lo; i < hi; ++i) {
    const int d = deg[i];
    rowstart[i] = acc;
    cursor[i] = acc;
    acc += d;
  }
  if (hi == N) rowstart[N] = acc;
}

// ---------------------------------------------------------------------------
// bucket_edges: single int2 (8B) scatter per edge
// ---------------------------------------------------------------------------
__global__ __launch_bounds__(256) void bucket_edges(
    const int* __restrict__ idx_i, const int* __restrict__ idx_j,
    int* __restrict__ cursor, int2* __restrict__ ijperm, int E)
{
  const int stride = gridDim.x * blockDim.x;
  for (int e = blockIdx.x * blockDim.x + threadIdx.x; e < E; e += stride) {
    const int ii = idx_i[e];
    const int pos = atomicAdd(&cursor[ii], 1);
    ijperm[pos] = make_int2(ii, idx_j[e]);
  }
}

// ---------------------------------------------------------------------------
// F12 (CSR order), round-14: denom atomics REMOVED — node_fused now computes
// the softmax denominator itself from the CSR row (it reads every expl value
// anyway).  Kills 2M device-scope atomicAdds + the ii_r shuffles.
// ---------------------------------------------------------------------------
#define THS 72
__global__ __launch_bounds__(256) void edge_f12(
    const ushort_t* __restrict__ h_bf, const float* __restrict__ x,
    const int2* __restrict__ ijperm,
    const float* __restrict__ W_in, const float* __restrict__ b_in,
    const float* __restrict__ W_h, const float* __restrict__ b_h,
    const float* __restrict__ W_out, const float* __restrict__ b_out,
    const float* __restrict__ W_att, const float* __restrict__ b_att,
    float4* __restrict__ dirb, ushort_t* __restrict__ heb,
    float* __restrict__ expl, int E)
{
  __shared__ ushort_t sB1[8 * 512];    // 8 KB: W_in fragments (kc*2+nt)
  __shared__ ushort_t sB2[20 * 512];   // 20 KB: W_h fragments (kc*4+nt)
  __shared__ ushort_t tH[4][16 * THS]; // 9 KB: per-wave transpose tile

  const int tid = threadIdx.x;
  for (int idx = tid; idx < 8 * 512; idx += 256) {
    const int j = idx & 7;
    const int ln = (idx >> 3) & 63;
    const int f = idx >> 9;
    const int k = (f >> 1) * 32 + (ln >> 4) * 8 + j;
    const int col = (f & 1) * 16 + (ln & 15);
    sB1[idx] = (col < 20) ? f2bfu(W_in[k * 20 + col]) : (ushort_t)0;
  }
  for (int idx = tid; idx < 20 * 512; idx += 256) {
    const int j = idx & 7;
    const int ln = (idx >> 3) & 63;
    const int f = idx >> 9;
    const int k = (f >> 2) * 32 + (ln >> 4) * 8 + j;
    const int col = (f & 3) * 16 + (ln & 15);
    sB2[idx] = (k < 149) ? f2bfu(W_h[k * 64 + col]) : (ushort_t)0;
  }
  __syncthreads();

  const int gtid = blockIdx.x * blockDim.x + tid;
  const int wid = gtid >> 6;
  const int lane = tid & 63;
  const int w = tid >> 6;
  const int nw = (gridDim.x * blockDim.x) >> 6;
  const int l15 = lane & 15;
  const int q = lane >> 4;

  const ushort_t* b1l = sB1 + lane * 8;
  const ushort_t* b2l = sB2 + lane * 8;

  v8s bfr3[2][2];
  #pragma unroll
  for (int kc = 0; kc < 2; ++kc)
    #pragma unroll
    for (int nt = 0; nt < 2; ++nt)
      #pragma unroll
      for (int j = 0; j < 8; ++j) {
        const int k = kc * 32 + q * 8 + j;
        const int col = nt * 16 + l15;
        bfr3[kc][nt][j] = f2bfs(W_out[k * 32 + col]);
      }

  float bin[2], mu[2];
  #pragma unroll
  for (int nt = 0; nt < 2; ++nt) {
    const int col = nt * 16 + l15;
    bin[nt] = (col < 20) ? b_in[col] : 0.0f;
    mu[nt] = MU0 + (float)col * DMU;
  }
  float bias2[4];
  #pragma unroll
  for (int nt = 0; nt < 4; ++nt) bias2[nt] = b_h[nt * 16 + l15];
  float bias3[2];
  #pragma unroll
  for (int nt = 0; nt < 2; ++nt) bias3[nt] = b_out[nt * 16 + l15];

  v8s battf;
  #pragma unroll
  for (int j = 0; j < 8; ++j)
    battf[j] = (l15 < 4) ? f2bfs(W_att[(q * 8 + j) * 4 + l15]) : (short)0;
  const float bav = (l15 < 4) ? b_att[l15] : 0.0f;

  const int ntiles = (E + 15) >> 4;

  int iiC = 0, jjC = 0;
  v8s afr[4];
  float rCx = 0.f, rCy = 0.f, rCz = 0.f;
  if (wid < ntiles) {
    const int row0 = wid * 16 + l15;
    const int rowL0 = (row0 < E) ? row0 : (E - 1);
    const int2 ij = ijperm[rowL0];
    iiC = ij.x;
    jjC = ij.y;
    afr[0] = *(const v8s*)(h_bf + (size_t)iiC * 64 + q * 8);
    afr[1] = *(const v8s*)(h_bf + (size_t)iiC * 64 + 32 + q * 8);
    afr[2] = *(const v8s*)(h_bf + (size_t)jjC * 64 + q * 8);
    afr[3] = *(const v8s*)(h_bf + (size_t)jjC * 64 + 32 + q * 8);
    if (lane < 16) {
      rCx = x[jjC * 3 + 0] - x[iiC * 3 + 0];
      rCy = x[jjC * 3 + 1] - x[iiC * 3 + 1];
      rCz = x[jjC * 3 + 2] - x[iiC * 3 + 2];
    }
  }

  for (int t = wid; t < ntiles; t += nw) {
    const int tn = t + nw;
    int iiN = 0, jjN = 0;
    v8s nfr[4];
    float rNx = 0.f, rNy = 0.f, rNz = 0.f;
    if (tn < ntiles) {
      const int rowN = tn * 16 + l15;
      const int rowLN = (rowN < E) ? rowN : (E - 1);
      const int2 ij = ijperm[rowLN];
      iiN = ij.x;
      jjN = ij.y;
      nfr[0] = *(const v8s*)(h_bf + (size_t)iiN * 64 + q * 8);
      nfr[1] = *(const v8s*)(h_bf + (size_t)iiN * 64 + 32 + q * 8);
      nfr[2] = *(const v8s*)(h_bf + (size_t)jjN * 64 + q * 8);
      nfr[3] = *(const v8s*)(h_bf + (size_t)jjN * 64 + 32 + q * 8);
      if (lane < 16) {
        rNx = x[jjN * 3 + 0] - x[iiN * 3 + 0];
        rNy = x[jjN * 3 + 1] - x[iiN * 3 + 1];
        rNz = x[jjN * 3 + 2] - x[iiN * 3 + 2];
      }
    }

    const int row = t * 16 + l15;
    float dval = 0.0f;
    if (lane < 16) {
      const float s2 = rCx * rCx + rCy * rCy + rCz * rCz + EPSC;
      const float rv = __builtin_amdgcn_rsqf(s2);
      dval = s2 * rv;  // = sqrt(s2)
      if (row < E) {
        float4 dq;
        dq.x = rCx * rv; dq.y = rCy * rv; dq.z = rCz * rv; dq.w = dval;
        dirb[row] = dq;
      }
    }

    // M1: [16,128] x W_in
    v4f acc1[2];
    #pragma unroll
    for (int nt = 0; nt < 2; ++nt) {
      v4f a = {0.f, 0.f, 0.f, 0.f};
      #pragma unroll
      for (int kc = 0; kc < 4; ++kc) {
        const v8s bfrag = *(const v8s*)(b1l + (kc * 2 + nt) * 512);
        a = __builtin_amdgcn_mfma_f32_16x16x32_bf16(afr[kc], bfrag, a, 0, 0, 0);
      }
      acc1[nt] = a;
    }

    float dr[4], edr[4];
    #pragma unroll
    for (int r = 0; r < 4; ++r) {
      dr[r] = __shfl(dval, q * 4 + r);
      edr[r] = __expf(-dr[r]);
    }
    #pragma unroll
    for (int nt = 0; nt < 2; ++nt) {
      const int col = nt * 16 + l15;
      #pragma unroll
      for (int r = 0; r < 4; ++r) {
        ushort_t ov;
        if (col < 20) {
          const float tt = edr[r] - mu[nt];
          ov = f2bfu((acc1[nt][r] + bin[nt]) * __expf(-BETA * tt * tt));
        } else if (col == 20) {
          ov = f2bfu(dr[r]);
        } else {
          ov = 0;
        }
        tH[w][(q * 4 + r) * THS + col] = ov;
      }
    }
    __builtin_amdgcn_wave_barrier();

    const v8s afr4 = *(const v8s*)&tH[w][l15 * THS + q * 8];
    __builtin_amdgcn_wave_barrier();

    // M2: [16,160] x W_h
    v4f acc2[4];
    #pragma unroll
    for (int nt = 0; nt < 4; ++nt) {
      v4f a = {0.f, 0.f, 0.f, 0.f};
      #pragma unroll
      for (int kc = 0; kc < 4; ++kc) {
        const v8s bfrag = *(const v8s*)(b2l + (kc * 4 + nt) * 512);
        a = __builtin_amdgcn_mfma_f32_16x16x32_bf16(afr[kc], bfrag, a, 0, 0, 0);
      }
      const v8s bfrag4 = *(const v8s*)(b2l + (4 * 4 + nt) * 512);
      a = __builtin_amdgcn_mfma_f32_16x16x32_bf16(afr4, bfrag4, a, 0, 0, 0);
      acc2[nt] = a;
    }

    #pragma unroll
    for (int nt = 0; nt < 4; ++nt) {
      #pragma unroll
      for (int r = 0; r < 4; ++r)
        tH[w][(q * 4 + r) * THS + nt * 16 + l15] =
            f2bfu(siluf(acc2[nt][r] + bias2[nt]));
    }
    __builtin_amdgcn_wave_barrier();

    v8s af3[2];
    af3[0] = *(const v8s*)&tH[w][l15 * THS + q * 8];
    af3[1] = *(const v8s*)&tH[w][l15 * THS + 32 + q * 8];

    v4f acc3[2];
    #pragma unroll
    for (int nt = 0; nt < 2; ++nt) {
      v4f a = {0.f, 0.f, 0.f, 0.f};
      #pragma unroll
      for (int kc = 0; kc < 2; ++kc)
        a = __builtin_amdgcn_mfma_f32_16x16x32_bf16(af3[kc], bfr3[kc][nt], a, 0, 0, 0);
      acc3[nt] = a;
    }
    __builtin_amdgcn_wave_barrier();

    const int rowb = t * 16 + q * 4;
    #pragma unroll
    for (int nt = 0; nt < 2; ++nt) {
      const int col = nt * 16 + l15;
      #pragma unroll
      for (int r = 0; r < 4; ++r) {
        const ushort_t hv = f2bfu(acc3[nt][r] + bias3[nt]);
        tH[w][(q * 4 + r) * THS + col] = hv;
        if (rowb + r < E) heb[(size_t)(rowb + r) * 32 + col] = hv;
      }
    }
    __builtin_amdgcn_wave_barrier();

    const v8s afA = *(const v8s*)&tH[w][l15 * THS + q * 8];
    v4f az = {0.f, 0.f, 0.f, 0.f};
    const v4f aacc = __builtin_amdgcn_mfma_f32_16x16x32_bf16(afA, battf, az, 0, 0, 0);

    if (l15 < 4) {
      #pragma unroll
      for (int r = 0; r < 4; ++r) {
        if (rowb + r < E) {
          const float la = aacc[r] + bav;
          const float l = (la > 0.f) ? la : 2.0f * (__expf(0.5f * la) - 1.0f);
          expl[(size_t)(rowb + r) * 4 + l15] = __expf(l);
        }
      }
    }
    __builtin_amdgcn_wave_barrier();

    iiC = iiN; jjC = jjN;
    afr[0] = nfr[0]; afr[1] = nfr[1]; afr[2] = nfr[2]; afr[3] = nfr[3];
    rCx = rNx; rCy = rNy; rCz = rNz;
  }
}

// ---------------------------------------------------------------------------
// node_fused — best-measured body (grid 2048); round-14: computes the
// softmax denominator in-row (4 extra accumulators in the semantic loop)
// instead of loading the atomically-built denom buffer.
// ---------------------------------------------------------------------------
__global__ __launch_bounds__(256) void node_fused(
    const int* __restrict__ rowstart,
    const ushort_t* __restrict__ heb,
    const float* __restrict__ expl,
    const float4* __restrict__ dirb,
    const float* __restrict__ W_xmix, const float* __restrict__ w_vmix,
    ushort_t* __restrict__ hsem, float* __restrict__ norm2,
    float* __restrict__ dv_mean, int N)
{
  __shared__ ushort_t sBX[8 * 512];  // 8 KB: W_xmix fragments (h*2+nt)

  const int tid = threadIdx.x;
  for (int idx = tid; idx < 8 * 512; idx += 256) {
    const int j = idx & 7;
    const int ln = (idx >> 3) & 63;
    const int f = idx >> 9;
    const int k = (f >> 1) * 32 + (ln >> 4) * 8 + j;
    const int col = (f & 1) * 16 + (ln & 15);
    sBX[idx] = f2bfu(W_xmix[k * 32 + col]);
  }
  __syncthreads();

  const int gtid = blockIdx.x * blockDim.x + tid;
  const int wid = gtid >> 6;
  const int lane = tid & 63;
  const int nw = (gridDim.x * blockDim.x) >> 6;
  const int l15 = lane & 15;
  const int q = lane >> 4;      // also the 4-edge subgroup
  const ushort_t* bXl = sBX + lane * 8;

  const float wv0 = w_vmix[l15];
  const float wv1 = w_vmix[16 + l15];

  // prefetch first node's CSR extent (wave-uniform -> SGPRs)
  int sC = 0, eC = 0;
  if (wid < N) {
    sC = rowstart[wid];
    eC = rowstart[wid + 1];
  }

  for (int n = wid; n < N; n += nw) {
    const int nn = n + nw;
    int sN = 0, eN = 0;
    if (nn < N) {
      sN = rowstart[nn];
      eN = rowstart[nn + 1];
    }
    const int s = sC;
    const int epd = eC;
    const int deg = epd - s;

    float invden[4];

    // ---- semantic aggregation + in-row denom: 4 edges/iter, coalesced ----
    {
      float sm00 = 0.f, sm01 = 0.f, sm10 = 0.f, sm11 = 0.f;
      float sm20 = 0.f, sm21 = 0.f, sm30 = 0.f, sm31 = 0.f;
      float dn0 = 0.f, dn1 = 0.f, dn2 = 0.f, dn3 = 0.f;
      int k = s;
      for (; k + 4 <= epd; k += 4) {
        const unsigned hv = ((const unsigned*)heb)[k * 16 + lane];
        const float4 ex = ((const float4*)expl)[k + q];
        const float h0 = bf2f((ushort_t)(hv & 0xffffu));
        const float h1 = bf2f((ushort_t)(hv >> 16));
        sm00 += ex.x * h0; sm01 += ex.x * h1;
        sm10 += ex.y * h0; sm11 += ex.y * h1;
        sm20 += ex.z * h0; sm21 += ex.z * h1;
        sm30 += ex.w * h0; sm31 += ex.w * h1;
        dn0 += ex.x; dn1 += ex.y; dn2 += ex.z; dn3 += ex.w;
      }
      if (k < epd) {
        const int ke = k + q;
        const int kl = (ke < epd) ? ke : (epd - 1);
        const float live = (ke < epd) ? 1.0f : 0.0f;
        const unsigned hv = ((const unsigned*)heb)[kl * 16 + l15];
        const float4 ex = ((const float4*)expl)[kl];
        const float h0 = bf2f((ushort_t)(hv & 0xffffu)) * live;
        const float h1 = bf2f((ushort_t)(hv >> 16)) * live;
        sm00 += ex.x * h0; sm01 += ex.x * h1;
        sm10 += ex.y * h0; sm11 += ex.y * h1;
        sm20 += ex.z * h0; sm21 += ex.z * h1;
        sm30 += ex.w * h0; sm31 += ex.w * h1;
        dn0 += ex.x * live; dn1 += ex.y * live;
        dn2 += ex.z * live; dn3 += ex.w * live;
      }
      // reduce across the 4 edge subgroups (lanes xor 16, 32)
      dn0 += __shfl_xor(dn0, 16); dn0 += __shfl_xor(dn0, 32);
      dn1 += __shfl_xor(dn1, 16); dn1 += __shfl_xor(dn1, 32);
      dn2 += __shfl_xor(dn2, 16); dn2 += __shfl_xor(dn2, 32);
      dn3 += __shfl_xor(dn3, 16); dn3 += __shfl_xor(dn3, 32);
      invden[0] = __builtin_amdgcn_rcpf(dn0 + EPSC);
      invden[1] = __builtin_amdgcn_rcpf(dn1 + EPSC);
      invden[2] = __builtin_amdgcn_rcpf(dn2 + EPSC);
      invden[3] = __builtin_amdgcn_rcpf(dn3 + EPSC);
      sm00 += __shfl_xor(sm00, 16); sm00 += __shfl_xor(sm00, 32);
      sm01 += __shfl_xor(sm01, 16); sm01 += __shfl_xor(sm01, 32);
      sm10 += __shfl_xor(sm10, 16); sm10 += __shfl_xor(sm10, 32);
      sm11 += __shfl_xor(sm11, 16); sm11 += __shfl_xor(sm11, 32);
      sm20 += __shfl_xor(sm20, 16); sm20 += __shfl_xor(sm20, 32);
      sm21 += __shfl_xor(sm21, 16); sm21 += __shfl_xor(sm21, 32);
      sm30 += __shfl_xor(sm30, 16); sm30 += __shfl_xor(sm30, 32);
      sm31 += __shfl_xor(sm31, 16); sm31 += __shfl_xor(sm31, 32);
      // lane (g=q, cp=l15) writes head q, channels 2cp, 2cp+1
      const float sa = (q & 2) ? ((q & 1) ? sm30 : sm20)
                               : ((q & 1) ? sm10 : sm00);
      const float sb = (q & 2) ? ((q & 1) ? sm31 : sm21)
                               : ((q & 1) ? sm11 : sm01);
      const float idn = (q & 2) ? ((q & 1) ? invden[3] : invden[2])
                                : ((q & 1) ? invden[1] : invden[0]);
      const unsigned pack = (unsigned)f2bfu(sa * idn) |
                            ((unsigned)f2bfu(sb * idn) << 16);
      ((unsigned*)hsem)[n * 64 + lane] = pack;
    }

    // ---- spatial mix + comb reductions, 16-edge MFMA chunks ----
    float cx0 = 0.f, cy0 = 0.f, cz0 = 0.f;   // comb col = l15
    float cx1 = 0.f, cy1 = 0.f, cz1 = 0.f;   // comb col = 16+l15

    for (int c0 = 0; c0 < deg; c0 += 16) {
      const int ra = c0 + l15;
      const int eA = s + ((ra < deg) ? ra : (deg - 1));
      const v8s hech = *(const v8s*)(heb + eA * 32 + q * 8);

      // y[h][nt] = (heb chunk) @ Wx_h  (raw bf16 A-operand)
      v4f y[4][2];
      #pragma unroll
      for (int h4 = 0; h4 < 4; ++h4) {
        #pragma unroll
        for (int nt = 0; nt < 2; ++nt) {
          v4f z = {0.f, 0.f, 0.f, 0.f};
          y[h4][nt] = __builtin_amdgcn_mfma_f32_16x16x32_bf16(
              hech, *(const v8s*)(bXl + (h4 * 2 + nt) * 512), z, 0, 0, 0);
        }
      }

      #pragma unroll
      for (int r = 0; r < 4; ++r) {
        const int rr = c0 + q * 4 + r;
        const int live = rr < deg;
        const int eR = s + (live ? rr : (deg - 1));
        const float lf = live ? 1.0f : 0.0f;
        const float4 ex4 = *(const float4*)(expl + eR * 4);
        const float at0 = ex4.x * invden[0] * lf;
        const float at1 = ex4.y * invden[1] * lf;
        const float at2 = ex4.z * invden[2] * lf;
        const float at3 = ex4.w * invden[3] * lf;
        const float p0 = at0 * y[0][0][r] + at1 * y[1][0][r] +
                         at2 * y[2][0][r] + at3 * y[3][0][r];
        const float p1 = at0 * y[0][1][r] + at1 * y[1][1][r] +
                         at2 * y[2][1][r] + at3 * y[3][1][r];
        const float4 dq = dirb[eR];
        const float m0 = tanhfast(p0);   // = 0 for pad rows (p = 0)
        const float m1 = tanhfast(p1);
        cx0 += dq.x * m0; cy0 += dq.y * m0; cz0 += dq.z * m0;
        cx1 += dq.x * m1; cy1 += dq.y * m1; cz1 += dq.z * m1;
      }
    }

    // reduce comb over the 4 q-groups
    cx0 += __shfl_xor(cx0, 16); cx0 += __shfl_xor(cx0, 32);
    cy0 += __shfl_xor(cy0, 16); cy0 += __shfl_xor(cy0, 32);
    cz0 += __shfl_xor(cz0, 16); cz0 += __shfl_xor(cz0, 32);
    cx1 += __shfl_xor(cx1, 16); cx1 += __shfl_xor(cx1, 32);
    cy1 += __shfl_xor(cy1, 16); cy1 += __shfl_xor(cy1, 32);
    cz1 += __shfl_xor(cz1, 16); cz1 += __shfl_xor(cz1, 32);

    const float cinv = __builtin_amdgcn_rcpf(fmaxf((float)deg, 1.0f));

    // norm2: lanes 0..31 write one coalesced row (col = lane)
    if (lane < 32) {
      const float mx = ((lane & 16) ? cx1 : cx0) * cinv;
      const float my = ((lane & 16) ? cy1 : cy0) * cinv;
      const float mz = ((lane & 16) ? cz1 : cz0) * cinv;
      norm2[n * 32 + lane] = mx * mx + my * my + mz * mz;
    }

    // dv = sum_c wv[c] * comb[c] * cinv   (identity)
    float tx = wv0 * cx0 + wv1 * cx1;
    float ty = wv0 * cy0 + wv1 * cy1;
    float tz = wv0 * cz0 + wv1 * cz1;
    tx += __shfl_xor(tx, 1); tx += __shfl_xor(tx, 2);
    tx += __shfl_xor(tx, 4); tx += __shfl_xor(tx, 8);
    ty += __shfl_xor(ty, 1); ty += __shfl_xor(ty, 2);
    ty += __shfl_xor(ty, 4); ty += __shfl_xor(ty, 8);
    tz += __shfl_xor(tz, 1); tz += __shfl_xor(tz, 2);
    tz += __shfl_xor(tz, 4); tz += __shfl_xor(tz, 8);
    if (lane == 0) {
      dv_mean[n * 3 + 0] = tx * cinv;
      dv_mean[n * 3 + 1] = ty * cinv;
      dv_mean[n * 3 + 2] = tz * cinv;
    }

    sC = sN; eC = eN;
  }
}

// ---------------------------------------------------------------------------
// C1 (MFMA): spatial MLP (post1/post2) + node1 -> nh bf16 [N,128]
// (best-measured: sW1t in LDS, grid 512)
// ---------------------------------------------------------------------------
#define W1S 232
__global__ __launch_bounds__(256) void node_c1_mfma(
    const ushort_t* __restrict__ h_bf, const ushort_t* __restrict__ hsem,
    const float* __restrict__ norm2,
    const float* __restrict__ W_post1, const float* __restrict__ b_post1,
    const float* __restrict__ W_post2, const float* __restrict__ b_post2,
    const float* __restrict__ W_node1, const float* __restrict__ b_node1,
    ushort_t* __restrict__ nh_out, int N)
{
  __shared__ ushort_t sW1t[128 * W1S];
  __shared__ ushort_t tp[4][16 * THS];

  const int tid = threadIdx.x;
  for (int idx = tid; idx < 224 * 128; idx += 256) {
    const int k = idx >> 7;
    const int c = idx & 127;
    sW1t[c * W1S + k] = f2bfu(W_node1[idx]);
  }
  __syncthreads();

  const int lane = tid & 63;
  const int w = tid >> 6;
  const int l15 = lane & 15;
  const int q = lane >> 4;

  v8s bp1[4];
  #pragma unroll
  for (int nt = 0; nt < 4; ++nt)
    #pragma unroll
    for (int j = 0; j < 8; ++j)
      bp1[nt][j] = f2bfs(W_post1[(q * 8 + j) * 64 + nt * 16 + l15]);
  v8s bp2[2][2];
  #pragma unroll
  for (int kc = 0; kc < 2; ++kc)
    #pragma unroll
    for (int nt = 0; nt < 2; ++nt)
      #pragma unroll
      for (int j = 0; j < 8; ++j)
        bp2[kc][nt][j] = f2bfs(W_post2[(kc * 32 + q * 8 + j) * 32 + nt * 16 + l15]);
  float bb1[4];
  #pragma unroll
  for (int nt = 0; nt < 4; ++nt) bb1[nt] = b_post1[nt * 16 + l15];
  float bb2[2];
  #pragma unroll
  for (int nt = 0; nt < 2; ++nt) bb2[nt] = b_post2[nt * 16 + l15];
  float b1[8];
  #pragma unroll
  for (int nt = 0; nt < 8; ++nt) b1[nt] = b_node1[nt * 16 + l15];

  const int gw = blockIdx.x * 4 + w;
  const int nwv = gridDim.x * 4;
  const int ntiles = (N + 15) >> 4;

  for (int t = gw; t < ntiles; t += nwv) {
    const int row = t * 16 + l15;
    const int rowL = (row < N) ? row : (N - 1);

    const float4 nA = *(const float4*)(norm2 + (size_t)rowL * 32 + q * 8);
    const float4 nB = *(const float4*)(norm2 + (size_t)rowL * 32 + q * 8 + 4);
    v8s a1;
    a1[0] = f2bfs(nA.x); a1[1] = f2bfs(nA.y);
    a1[2] = f2bfs(nA.z); a1[3] = f2bfs(nA.w);
    a1[4] = f2bfs(nB.x); a1[5] = f2bfs(nB.y);
    a1[6] = f2bfs(nB.z); a1[7] = f2bfs(nB.w);

    v4f p1[4];
    #pragma unroll
    for (int nt = 0; nt < 4; ++nt) {
      v4f a = {0.f, 0.f, 0.f, 0.f};
      p1[nt] = __builtin_amdgcn_mfma_f32_16x16x32_bf16(a1, bp1[nt], a, 0, 0, 0);
    }
    #pragma unroll
    for (int nt = 0; nt < 4; ++nt)
      #pragma unroll
      for (int r = 0; r < 4; ++r)
        tp[w][(q * 4 + r) * THS + nt * 16 + l15] =
            f2bfu(siluf(p1[nt][r] + bb1[nt]));
    __builtin_amdgcn_wave_barrier();

    v8s a2[2];
    a2[0] = *(const v8s*)&tp[w][l15 * THS + q * 8];
    a2[1] = *(const v8s*)&tp[w][l15 * THS + 32 + q * 8];

    v4f p2[2];
    #pragma unroll
    for (int nt = 0; nt < 2; ++nt) {
      v4f a = {0.f, 0.f, 0.f, 0.f};
      #pragma unroll
      for (int kc = 0; kc < 2; ++kc)
        a = __builtin_amdgcn_mfma_f32_16x16x32_bf16(a2[kc], bp2[kc][nt], a, 0, 0, 0);
      p2[nt] = a;
    }
    __builtin_amdgcn_wave_barrier();
    #pragma unroll
    for (int nt = 0; nt < 2; ++nt)
      #pragma unroll
      for (int r = 0; r < 4; ++r)
        tp[w][(q * 4 + r) * THS + nt * 16 + l15] =
            f2bfu(siluf(p2[nt][r] + bb2[nt]));
    __builtin_amdgcn_wave_barrier();

    v8s af[7];
    af[0] = *(const v8s*)(h_bf + (size_t)rowL * 64 + q * 8);
    af[1] = *(const v8s*)(h_bf + (size_t)rowL * 64 + 32 + q * 8);
    #pragma unroll
    for (int kc = 0; kc < 4; ++kc)
      af[2 + kc] = *(const v8s*)(hsem + (size_t)rowL * 128 + kc * 32 + q * 8);
    af[6] = *(const v8s*)&tp[w][l15 * THS + q * 8];

    v4f acc[8];
    #pragma unroll
    for (int nt = 0; nt < 8; ++nt) acc[nt] = (v4f){0.f, 0.f, 0.f, 0.f};
    #pragma unroll
    for (int kc = 0; kc < 7; ++kc) {
      #pragma unroll
      for (int nt = 0; nt < 8; ++nt) {
        const v8s bfrag =
            *(const v8s*)&sW1t[(nt * 16 + l15) * W1S + kc * 32 + q * 8];
        acc[nt] = __builtin_amdgcn_mfma_f32_16x16x32_bf16(af[kc], bfrag, acc[nt], 0, 0, 0);
      }
    }

    const int rowb = t * 16 + q * 4;
    #pragma unroll
    for (int nt = 0; nt < 8; ++nt) {
      #pragma unroll
      for (int r = 0; r < 4; ++r)
        if (rowb + r < N)
          nh_out[(size_t)(rowb + r) * 128 + nt * 16 + l15] =
              f2bfu(siluf(acc[nt][r] + b1[nt]));
    }
  }
}

// ---------------------------------------------------------------------------
// C2 (MFMA): node2 + vel1 + gate + v/x update (dv_mean precomputed)
// (best-measured: grid 512)
// ---------------------------------------------------------------------------
__global__ __launch_bounds__(256) void node_c2_mfma(
    const float* __restrict__ h, const float* __restrict__ x,
    const float* __restrict__ v, const ushort_t* __restrict__ nh,
    const float* __restrict__ dv_mean,
    const float* __restrict__ W_node2, const float* __restrict__ b_node2,
    const float* __restrict__ W_vel1, const float* __restrict__ b_vel1,
    const float* __restrict__ W_vel2,
    float* __restrict__ out, int N)
{
  __shared__ ushort_t sW2[16 * 64 * 8];
  __shared__ ushort_t sWv[4 * 64 * 8];
  __shared__ ushort_t tH[4][16 * THS];
  __shared__ float sg[4][16];

  const int tid = threadIdx.x;
  for (int idx = tid; idx < 16 * 64 * 8; idx += 256) {
    const int j = idx & 7;
    const int ln = (idx >> 3) & 63;
    const int f = idx >> 9;
    const int k = (f >> 2) * 32 + (ln >> 4) * 8 + j;
    const int col = (f & 3) * 16 + (ln & 15);
    sW2[idx] = f2bfu(W_node2[k * 64 + col]);
  }
  for (int idx = tid; idx < 4 * 64 * 8; idx += 256) {
    const int j = idx & 7;
    const int ln = (idx >> 3) & 63;
    const int f = idx >> 9;
    const int k = (f >> 1) * 32 + (ln >> 4) * 8 + j;
    const int col = (f & 1) * 16 + (ln & 15);
    sWv[idx] = f2bfu(W_vel1[k * 32 + col]);
  }
  __syncthreads();

  const int lane = tid & 63;
  const int w = tid >> 6;
  const int l15 = lane & 15;
  const int q = lane >> 4;

  const ushort_t* w2l = sW2 + lane * 8;
  const ushort_t* wvl = sWv + lane * 8;

  float b2[4];
  #pragma unroll
  for (int nt = 0; nt < 4; ++nt) b2[nt] = b_node2[nt * 16 + l15];
  float bv[2];
  #pragma unroll
  for (int nt = 0; nt < 2; ++nt) bv[nt] = b_vel1[nt * 16 + l15];
  float wv2[2];
  #pragma unroll
  for (int nt = 0; nt < 2; ++nt) wv2[nt] = W_vel2[nt * 16 + l15];

  const int gw = blockIdx.x * 4 + w;
  const int nwv = gridDim.x * 4;
  const int ntiles = (N + 15) >> 4;

  for (int t = gw; t < ntiles; t += nwv) {
    const int row = t * 16 + l15;
    const int rowL = (row < N) ? row : (N - 1);

    v8s af[4];
    #pragma unroll
    for (int kc = 0; kc < 4; ++kc)
      af[kc] = *(const v8s*)(nh + (size_t)rowL * 128 + kc * 32 + q * 8);

    v4f acc[4];
    #pragma unroll
    for (int nt = 0; nt < 4; ++nt) {
      v4f a = {0.f, 0.f, 0.f, 0.f};
      #pragma unroll
      for (int kc = 0; kc < 4; ++kc) {
        const v8s bfrag = *(const v8s*)(w2l + (kc * 4 + nt) * 512);
        a = __builtin_amdgcn_mfma_f32_16x16x32_bf16(af[kc], bfrag, a, 0, 0, 0);
      }
      acc[nt] = a;
    }

    const int rowb = t * 16 + q * 4;
    #pragma unroll
    for (int nt = 0; nt < 4; ++nt) {
      const int col = nt * 16 + l15;
      #pragma unroll
      for (int r = 0; r < 4; ++r) {
        const int n = rowb + r;
        if (n < N) {
          const float hu = h[(size_t)n * 64 + col] + siluf(acc[nt][r] + b2[nt]);
          out[(size_t)n * 64 + col] = hu;
          tH[w][(q * 4 + r) * THS + col] = f2bfu(hu);
        }
      }
    }
    __builtin_amdgcn_wave_barrier();

    v8s a2[2];
    a2[0] = *(const v8s*)&tH[w][l15 * THS + q * 8];
    a2[1] = *(const v8s*)&tH[w][l15 * THS + 32 + q * 8];
    v4f av[2];
    #pragma unroll
    for (int nt = 0; nt < 2; ++nt) {
      v4f a = {0.f, 0.f, 0.f, 0.f};
      #pragma unroll
      for (int kc = 0; kc < 2; ++kc) {
        const v8s bfrag = *(const v8s*)(wvl + (kc * 2 + nt) * 512);
        a = __builtin_amdgcn_mfma_f32_16x16x32_bf16(a2[kc], bfrag, a, 0, 0, 0);
      }
      av[nt] = a;
    }

    #pragma unroll
    for (int r = 0; r < 4; ++r) {
      float pr = siluf(av[0][r] + bv[0]) * wv2[0] +
                 siluf(av[1][r] + bv[1]) * wv2[1];
      pr += __shfl_xor(pr, 1);
      pr += __shfl_xor(pr, 2);
      pr += __shfl_xor(pr, 4);
      pr += __shfl_xor(pr, 8);
      if (l15 == 0)
        sg[w][q * 4 + r] = 2.0f * __builtin_amdgcn_rcpf(1.0f + __expf(-pr));
    }
    __builtin_amdgcn_wave_barrier();

    if (lane < 48) {
      const int rr = lane / 3;
      const int c = lane % 3;
      const int n = t * 16 + rr;
      if (n < N) {
        const float gate = sg[w][rr];
        const float dv = dv_mean[n * 3 + c];
        const float vu = gate * v[n * 3 + c] + dv;
        out[(size_t)N * 64 + (size_t)n * 3 + c] = x[n * 3 + c] + vu;
        out[(size_t)N * 64 + (size_t)N * 3 + (size_t)n * 3 + c] = vu;
      }
    }
    __builtin_amdgcn_wave_barrier();
  }
}

// ---------------------------------------------------------------------------
extern "C" void kernel_launch(void* const* d_in, const int* in_sizes, int n_in,
                              void* d_out, int out_size, void* d_ws, size_t ws_size,
                              hipStream_t stream) {
  const float* h   = (const float*)d_in[0];
  const float* x   = (const float*)d_in[1];
  const float* v   = (const float*)d_in[2];
  const int* idx_i = (const int*)d_in[3];
  const int* idx_j = (const int*)d_in[4];
  const float* W_edge_in  = (const float*)d_in[5];
  const float* b_edge_in  = (const float*)d_in[6];
  const float* W_edge_h   = (const float*)d_in[7];
  const float* b_edge_h   = (const float*)d_in[8];
  const float* W_edge_out = (const float*)d_in[9];
  const float* b_edge_out = (const float*)d_in[10];
  const float* W_att      = (const float*)d_in[11];
  const float* b_att      = (const float*)d_in[12];
  const float* W_x_mix    = (const float*)d_in[13];
  const float* W_node1    = (const float*)d_in[14];
  const float* b_node1    = (const float*)d_in[15];
  const float* W_node2    = (const float*)d_in[16];
  const float* b_node2    = (const float*)d_in[17];
  const float* W_post1    = (const float*)d_in[18];
  const float* b_post1    = (const float*)d_in[19];
  const float* W_post2    = (const float*)d_in[20];
  const float* b_post2    = (const float*)d_in[21];
  const float* W_vel1     = (const float*)d_in[22];
  const float* b_vel1     = (const float*)d_in[23];
  const float* W_vel2     = (const float*)d_in[24];
  const float* w_v_mix    = (const float*)d_in[25];

  const int E = in_sizes[3];
  const int N = in_sizes[0] / DA;

  float* ws = (float*)d_ws;
  size_t off = 0;
  int*   deg      = (int*)(ws + off); off += (size_t)N; // zeroed
  const size_t zeroBytes = off * sizeof(float);
  int*   rowstart = (int*)(ws + off); off += (size_t)N + 4;
  int*   cursor   = (int*)(ws + off); off += (size_t)N;
  int*   tsum     = (int*)(ws + off); off += (size_t)SCAN_T;
  int2*  ijperm   = (int2*)(ws + off); off += (size_t)E * 2;
  float* expl     = ws + off; off += (size_t)E * 4;
  float* dirbR    = ws + off; off += (size_t)E * 4;
  float* hsemR    = ws + off; off += (size_t)N * 64;
  float* norm2    = ws + off; off += (size_t)N * 32;
  float* dv_mean  = ws + off; off += (size_t)N * 4;
  float* hbfR     = ws + off; off += (size_t)N * 32;
  float* fltR     = ws + off; off += (size_t)E * 16;    // nh
  float* hebR     = ws + off; off += (size_t)E * 16;

  ushort_t* h_bf = (ushort_t*)hbfR;
  ushort_t* hsem = (ushort_t*)hsemR;
  ushort_t* heb  = (ushort_t*)hebR;
  ushort_t* nh   = (ushort_t*)fltR;
  float4*   dirb = (float4*)dirbR;

  hipMemsetAsync(d_ws, 0, zeroBytes, stream);

  {
    const int n4 = (N * 64) / 4;
    cast_count<<<1024, 256, 0, stream>>>(h, h_bf, n4, idx_i, deg, E);
  }
  {
    const int C = (N + SCAN_T - 1) / SCAN_T;
    deg_tsum<<<SCAN_B, 256, 0, stream>>>(deg, tsum, N, C);
    scan_tsum<<<1, 256, 0, stream>>>(tsum);
    write_csr<<<SCAN_B, 256, 0, stream>>>(deg, tsum, rowstart, cursor, N, C);
  }
  bucket_edges<<<512, 256, 0, stream>>>(idx_i, idx_j, cursor, ijperm, E);
  edge_f12<<<1024, 256, 0, stream>>>(h_bf, x, ijperm,
                                     W_edge_in, b_edge_in, W_edge_h, b_edge_h,
                                     W_edge_out, b_edge_out, W_att, b_att,
                                     dirb, heb, expl, E);
  node_fused<<<2048, 256, 0, stream>>>(rowstart, heb, expl, dirb,
                                       W_x_mix, w_v_mix, hsem, norm2,
                                       dv_mean, N);
  node_c1_mfma<<<512, 256, 0, stream>>>(
      h_bf, hsem, norm2, W_post1, b_post1, W_post2, b_post2,
      W_node1, b_node1, nh, N);
  node_c2_mfma<<<512, 256, 0, stream>>>(
      h, x, v, nh, dv_mean, W_node2, b_node2, W_vel1, b_vel1, W_vel2,
      (float*)d_out, N);
}

// Round 15
// 345.140 us; speedup vs baseline: 1.1217x; 1.1217x over previous
//
#include <hip/hip_runtime.h>
#include <math.h>

#define DA 64
#define EPSC 1e-8f

typedef short v8s __attribute__((ext_vector_type(8)));
typedef float v4f __attribute__((ext_vector_type(4)));
typedef unsigned short ushort_t;

// fast silu: v * rcp(1+exp(-v))
__device__ __forceinline__ float siluf(float v) {
  return v * __builtin_amdgcn_rcpf(1.0f + __expf(-v));
}
// fast tanh: 1 - 2*rcp(exp(2x)+1)
__device__ __forceinline__ float tanhfast(float x) {
  return 1.0f - 2.0f * __builtin_amdgcn_rcpf(__expf(2.0f * x) + 1.0f);
}

__device__ __forceinline__ void atomAddF(float* p, float v) {
#if defined(__HIP_DEVICE_COMPILE__)
  unsafeAtomicAdd(p, v);
#else
  atomicAdd(p, v);
#endif
}

__device__ __forceinline__ unsigned short f2bfu(float f) {
  union { float f; unsigned u; } v; v.f = f;
  unsigned r = v.u + 0x7fffu + ((v.u >> 16) & 1u);
  return (unsigned short)(r >> 16);
}
__device__ __forceinline__ short f2bfs(float f) { return (short)f2bfu(f); }
__device__ __forceinline__ float bf2f(ushort_t s) {
  union { unsigned u; float f; } v; v.u = ((unsigned)s) << 16; return v.f;
}

#define MU0 0.60653065971263342f
#define DMU ((1.0f - 0.60653065971263342f) / 19.0f)
#define BETA ((float)(1.0 / (0.039346934028736658 * 0.039346934028736658)))

// ---------------------------------------------------------------------------
// fused: bf16 cast of h  +  degree count
// ---------------------------------------------------------------------------
__global__ __launch_bounds__(256) void cast_count(
    const float* __restrict__ hsrc, ushort_t* __restrict__ hb, int n4,
    const int* __restrict__ idx_i, int* __restrict__ deg, int E)
{
  const int stride = gridDim.x * blockDim.x;
  for (int i = blockIdx.x * blockDim.x + threadIdx.x; i < n4; i += stride) {
    const float4 fv = ((const float4*)hsrc)[i];
    ushort4 o;
    o.x = f2bfu(fv.x); o.y = f2bfu(fv.y); o.z = f2bfu(fv.z); o.w = f2bfu(fv.w);
    ((ushort4*)hb)[i] = o;
  }
  for (int e = blockIdx.x * blockDim.x + threadIdx.x; e < E; e += stride)
    atomicAdd(&deg[idx_i[e]], 1);
}

// ---------------------------------------------------------------------------
#define SCAN_B 64
#define SCAN_T (SCAN_B * 256)

__global__ __launch_bounds__(256) void deg_tsum(
    const int* __restrict__ deg, int* __restrict__ tsum, int N, int C)
{
  const int g = blockIdx.x * blockDim.x + threadIdx.x;
  const int lo = g * C;
  const int hi = (lo + C < N) ? (lo + C) : N;
  int s = 0;
  for (int i = lo; i < hi; ++i) s += deg[i];
  tsum[g] = s;
}

__global__ __launch_bounds__(256) void scan_tsum(int* __restrict__ tsum)
{
  __shared__ int ps[256];
  const int t = threadIdx.x;
  const int per = SCAN_T / 256;
  const int lo = t * per;
  int s = 0;
  for (int i = 0; i < per; ++i) s += tsum[lo + i];
  ps[t] = s;
  __syncthreads();
  if (t == 0) {
    int a = 0;
    for (int i = 0; i < 256; ++i) { const int v = ps[i]; ps[i] = a; a += v; }
  }
  __syncthreads();
  int acc = ps[t];
  for (int i = 0; i < per; ++i) {
    const int v = tsum[lo + i];
    tsum[lo + i] = acc;
    acc += v;
  }
}

__global__ __launch_bounds__(256) void write_csr(
    const int* __restrict__ deg, const int* __restrict__ tpre,
    int* __restrict__ rowstart, int* __restrict__ cursor, int N, int C)
{
  const int g = blockIdx.x * blockDim.x + threadIdx.x;
  const int lo = g * C;
  const int hi = (lo + C < N) ? (lo + C) : N;
  int acc = tpre[g];
  for (int i = lo; i < hi; ++i) {
    const int d = deg[i];
    rowstart[i] = acc;
    cursor[i] = acc;
    acc += d;
  }
  if (hi == N) rowstart[N] = acc;
}

// ---------------------------------------------------------------------------
// bucket_edges: single int2 (8B) scatter per edge
// ---------------------------------------------------------------------------
__global__ __launch_bounds__(256) void bucket_edges(
    const int* __restrict__ idx_i, const int* __restrict__ idx_j,
    int* __restrict__ cursor, int2* __restrict__ ijperm, int E)
{
  const int stride = gridDim.x * blockDim.x;
  for (int e = blockIdx.x * blockDim.x + threadIdx.x; e < E; e += stride) {
    const int ii = idx_i[e];
    const int pos = atomicAdd(&cursor[ii], 1);
    ijperm[pos] = make_int2(ii, idx_j[e]);
  }
}

// ---------------------------------------------------------------------------
// F12 (CSR order) — best-measured config.
// ---------------------------------------------------------------------------
#define THS 72
__global__ __launch_bounds__(256) void edge_f12(
    const ushort_t* __restrict__ h_bf, const float* __restrict__ x,
    const int2* __restrict__ ijperm,
    const float* __restrict__ W_in, const float* __restrict__ b_in,
    const float* __restrict__ W_h, const float* __restrict__ b_h,
    const float* __restrict__ W_out, const float* __restrict__ b_out,
    const float* __restrict__ W_att, const float* __restrict__ b_att,
    float4* __restrict__ dirb, ushort_t* __restrict__ heb,
    float* __restrict__ expl, float* __restrict__ denom, int E)
{
  __shared__ ushort_t sB1[8 * 512];    // 8 KB: W_in fragments (kc*2+nt)
  __shared__ ushort_t sB2[20 * 512];   // 20 KB: W_h fragments (kc*4+nt)
  __shared__ ushort_t tH[4][16 * THS]; // 9 KB: per-wave transpose tile

  const int tid = threadIdx.x;
  for (int idx = tid; idx < 8 * 512; idx += 256) {
    const int j = idx & 7;
    const int ln = (idx >> 3) & 63;
    const int f = idx >> 9;
    const int k = (f >> 1) * 32 + (ln >> 4) * 8 + j;
    const int col = (f & 1) * 16 + (ln & 15);
    sB1[idx] = (col < 20) ? f2bfu(W_in[k * 20 + col]) : (ushort_t)0;
  }
  for (int idx = tid; idx < 20 * 512; idx += 256) {
    const int j = idx & 7;
    const int ln = (idx >> 3) & 63;
    const int f = idx >> 9;
    const int k = (f >> 2) * 32 + (ln >> 4) * 8 + j;
    const int col = (f & 3) * 16 + (ln & 15);
    sB2[idx] = (k < 149) ? f2bfu(W_h[k * 64 + col]) : (ushort_t)0;
  }
  __syncthreads();

  const int gtid = blockIdx.x * blockDim.x + tid;
  const int wid = gtid >> 6;
  const int lane = tid & 63;
  const int w = tid >> 6;
  const int nw = (gridDim.x * blockDim.x) >> 6;
  const int l15 = lane & 15;
  const int q = lane >> 4;

  const ushort_t* b1l = sB1 + lane * 8;
  const ushort_t* b2l = sB2 + lane * 8;

  v8s bfr3[2][2];
  #pragma unroll
  for (int kc = 0; kc < 2; ++kc)
    #pragma unroll
    for (int nt = 0; nt < 2; ++nt)
      #pragma unroll
      for (int j = 0; j < 8; ++j) {
        const int k = kc * 32 + q * 8 + j;
        const int col = nt * 16 + l15;
        bfr3[kc][nt][j] = f2bfs(W_out[k * 32 + col]);
      }

  float bin[2], mu[2];
  #pragma unroll
  for (int nt = 0; nt < 2; ++nt) {
    const int col = nt * 16 + l15;
    bin[nt] = (col < 20) ? b_in[col] : 0.0f;
    mu[nt] = MU0 + (float)col * DMU;
  }
  float bias2[4];
  #pragma unroll
  for (int nt = 0; nt < 4; ++nt) bias2[nt] = b_h[nt * 16 + l15];
  float bias3[2];
  #pragma unroll
  for (int nt = 0; nt < 2; ++nt) bias3[nt] = b_out[nt * 16 + l15];

  v8s battf;
  #pragma unroll
  for (int j = 0; j < 8; ++j)
    battf[j] = (l15 < 4) ? f2bfs(W_att[(q * 8 + j) * 4 + l15]) : (short)0;
  const float bav = (l15 < 4) ? b_att[l15] : 0.0f;

  const int ntiles = (E + 15) >> 4;

  int iiC = 0, jjC = 0;
  v8s afr[4];
  float rCx = 0.f, rCy = 0.f, rCz = 0.f;
  if (wid < ntiles) {
    const int row0 = wid * 16 + l15;
    const int rowL0 = (row0 < E) ? row0 : (E - 1);
    const int2 ij = ijperm[rowL0];
    iiC = ij.x;
    jjC = ij.y;
    afr[0] = *(const v8s*)(h_bf + (size_t)iiC * 64 + q * 8);
    afr[1] = *(const v8s*)(h_bf + (size_t)iiC * 64 + 32 + q * 8);
    afr[2] = *(const v8s*)(h_bf + (size_t)jjC * 64 + q * 8);
    afr[3] = *(const v8s*)(h_bf + (size_t)jjC * 64 + 32 + q * 8);
    if (lane < 16) {
      rCx = x[jjC * 3 + 0] - x[iiC * 3 + 0];
      rCy = x[jjC * 3 + 1] - x[iiC * 3 + 1];
      rCz = x[jjC * 3 + 2] - x[iiC * 3 + 2];
    }
  }

  for (int t = wid; t < ntiles; t += nw) {
    const int tn = t + nw;
    int iiN = 0, jjN = 0;
    v8s nfr[4];
    float rNx = 0.f, rNy = 0.f, rNz = 0.f;
    if (tn < ntiles) {
      const int rowN = tn * 16 + l15;
      const int rowLN = (rowN < E) ? rowN : (E - 1);
      const int2 ij = ijperm[rowLN];
      iiN = ij.x;
      jjN = ij.y;
      nfr[0] = *(const v8s*)(h_bf + (size_t)iiN * 64 + q * 8);
      nfr[1] = *(const v8s*)(h_bf + (size_t)iiN * 64 + 32 + q * 8);
      nfr[2] = *(const v8s*)(h_bf + (size_t)jjN * 64 + q * 8);
      nfr[3] = *(const v8s*)(h_bf + (size_t)jjN * 64 + 32 + q * 8);
      if (lane < 16) {
        rNx = x[jjN * 3 + 0] - x[iiN * 3 + 0];
        rNy = x[jjN * 3 + 1] - x[iiN * 3 + 1];
        rNz = x[jjN * 3 + 2] - x[iiN * 3 + 2];
      }
    }

    const int row = t * 16 + l15;
    float dval = 0.0f;
    if (lane < 16) {
      const float s2 = rCx * rCx + rCy * rCy + rCz * rCz + EPSC;
      const float rv = __builtin_amdgcn_rsqf(s2);
      dval = s2 * rv;  // = sqrt(s2)
      if (row < E) {
        float4 dq;
        dq.x = rCx * rv; dq.y = rCy * rv; dq.z = rCz * rv; dq.w = dval;
        dirb[row] = dq;
      }
    }

    // M1: [16,128] x W_in
    v4f acc1[2];
    #pragma unroll
    for (int nt = 0; nt < 2; ++nt) {
      v4f a = {0.f, 0.f, 0.f, 0.f};
      #pragma unroll
      for (int kc = 0; kc < 4; ++kc) {
        const v8s bfrag = *(const v8s*)(b1l + (kc * 2 + nt) * 512);
        a = __builtin_amdgcn_mfma_f32_16x16x32_bf16(afr[kc], bfrag, a, 0, 0, 0);
      }
      acc1[nt] = a;
    }

    float dr[4], edr[4];
    #pragma unroll
    for (int r = 0; r < 4; ++r) {
      dr[r] = __shfl(dval, q * 4 + r);
      edr[r] = __expf(-dr[r]);
    }
    #pragma unroll
    for (int nt = 0; nt < 2; ++nt) {
      const int col = nt * 16 + l15;
      #pragma unroll
      for (int r = 0; r < 4; ++r) {
        ushort_t ov;
        if (col < 20) {
          const float tt = edr[r] - mu[nt];
          ov = f2bfu((acc1[nt][r] + bin[nt]) * __expf(-BETA * tt * tt));
        } else if (col == 20) {
          ov = f2bfu(dr[r]);
        } else {
          ov = 0;
        }
        tH[w][(q * 4 + r) * THS + col] = ov;
      }
    }
    __builtin_amdgcn_wave_barrier();

    const v8s afr4 = *(const v8s*)&tH[w][l15 * THS + q * 8];
    __builtin_amdgcn_wave_barrier();

    // M2: [16,160] x W_h
    v4f acc2[4];
    #pragma unroll
    for (int nt = 0; nt < 4; ++nt) {
      v4f a = {0.f, 0.f, 0.f, 0.f};
      #pragma unroll
      for (int kc = 0; kc < 4; ++kc) {
        const v8s bfrag = *(const v8s*)(b2l + (kc * 4 + nt) * 512);
        a = __builtin_amdgcn_mfma_f32_16x16x32_bf16(afr[kc], bfrag, a, 0, 0, 0);
      }
      const v8s bfrag4 = *(const v8s*)(b2l + (4 * 4 + nt) * 512);
      a = __builtin_amdgcn_mfma_f32_16x16x32_bf16(afr4, bfrag4, a, 0, 0, 0);
      acc2[nt] = a;
    }

    #pragma unroll
    for (int nt = 0; nt < 4; ++nt) {
      #pragma unroll
      for (int r = 0; r < 4; ++r)
        tH[w][(q * 4 + r) * THS + nt * 16 + l15] =
            f2bfu(siluf(acc2[nt][r] + bias2[nt]));
    }
    __builtin_amdgcn_wave_barrier();

    v8s af3[2];
    af3[0] = *(const v8s*)&tH[w][l15 * THS + q * 8];
    af3[1] = *(const v8s*)&tH[w][l15 * THS + 32 + q * 8];

    v4f acc3[2];
    #pragma unroll
    for (int nt = 0; nt < 2; ++nt) {
      v4f a = {0.f, 0.f, 0.f, 0.f};
      #pragma unroll
      for (int kc = 0; kc < 2; ++kc)
        a = __builtin_amdgcn_mfma_f32_16x16x32_bf16(af3[kc], bfr3[kc][nt], a, 0, 0, 0);
      acc3[nt] = a;
    }
    __builtin_amdgcn_wave_barrier();

    const int rowb = t * 16 + q * 4;
    #pragma unroll
    for (int nt = 0; nt < 2; ++nt) {
      const int col = nt * 16 + l15;
      #pragma unroll
      for (int r = 0; r < 4; ++r) {
        const ushort_t hv = f2bfu(acc3[nt][r] + bias3[nt]);
        tH[w][(q * 4 + r) * THS + col] = hv;
        if (rowb + r < E) heb[(size_t)(rowb + r) * 32 + col] = hv;
      }
    }
    __builtin_amdgcn_wave_barrier();

    const v8s afA = *(const v8s*)&tH[w][l15 * THS + q * 8];
    v4f az = {0.f, 0.f, 0.f, 0.f};
    const v4f aacc = __builtin_amdgcn_mfma_f32_16x16x32_bf16(afA, battf, az, 0, 0, 0);

    int ii_r[4];
    #pragma unroll
    for (int r = 0; r < 4; ++r) ii_r[r] = __shfl(iiC, q * 4 + r);

    if (l15 < 4) {
      #pragma unroll
      for (int r = 0; r < 4; ++r) {
        if (rowb + r < E) {
          const float la = aacc[r] + bav;
          const float l = (la > 0.f) ? la : 2.0f * (__expf(0.5f * la) - 1.0f);
          const float ev = __expf(l);
          expl[(size_t)(rowb + r) * 4 + l15] = ev;
          atomAddF(&denom[ii_r[r] * 4 + l15], ev);
        }
      }
    }
    __builtin_amdgcn_wave_barrier();

    iiC = iiN; jjC = jjN;
    afr[0] = nfr[0]; afr[1] = nfr[1]; afr[2] = nfr[2]; afr[3] = nfr[3];
    rCx = rNx; rCy = rNy; rCz = rNz;
  }
}

// ---------------------------------------------------------------------------
// node_fused — best-measured body (grid-stride + SGPR rowstart prefetch,
// 4-edge semantic loop, denom float4).
// ---------------------------------------------------------------------------
__global__ __launch_bounds__(256) void node_fused(
    const int* __restrict__ rowstart,
    const ushort_t* __restrict__ heb,
    const float* __restrict__ expl, const float* __restrict__ denom,
    const float4* __restrict__ dirb,
    const float* __restrict__ W_xmix, const float* __restrict__ w_vmix,
    ushort_t* __restrict__ hsem, float* __restrict__ norm2,
    float* __restrict__ dv_mean, int N)
{
  __shared__ ushort_t sBX[8 * 512];  // 8 KB: W_xmix fragments (h*2+nt)

  const int tid = threadIdx.x;
  for (int idx = tid; idx < 8 * 512; idx += 256) {
    const int j = idx & 7;
    const int ln = (idx >> 3) & 63;
    const int f = idx >> 9;
    const int k = (f >> 1) * 32 + (ln >> 4) * 8 + j;
    const int col = (f & 1) * 16 + (ln & 15);
    sBX[idx] = f2bfu(W_xmix[k * 32 + col]);
  }
  __syncthreads();

  const int gtid = blockIdx.x * blockDim.x + tid;
  const int wid = gtid >> 6;
  const int lane = tid & 63;
  const int nw = (gridDim.x * blockDim.x) >> 6;
  const int l15 = lane & 15;
  const int q = lane >> 4;      // also the 4-edge subgroup
  const ushort_t* bXl = sBX + lane * 8;

  const float wv0 = w_vmix[l15];
  const float wv1 = w_vmix[16 + l15];

  // prefetch first node's CSR extent (wave-uniform -> SGPRs)
  int sC = 0, eC = 0;
  if (wid < N) {
    sC = rowstart[wid];
    eC = rowstart[wid + 1];
  }

  for (int n = wid; n < N; n += nw) {
    const int nn = n + nw;
    int sN = 0, eN = 0;
    if (nn < N) {
      sN = rowstart[nn];
      eN = rowstart[nn + 1];
    }
    const int s = sC;
    const int epd = eC;
    const int deg = epd - s;

    const float4 dnm = *(const float4*)(denom + n * 4);
    float invden[4];
    invden[0] = __builtin_amdgcn_rcpf(dnm.x + EPSC);
    invden[1] = __builtin_amdgcn_rcpf(dnm.y + EPSC);
    invden[2] = __builtin_amdgcn_rcpf(dnm.z + EPSC);
    invden[3] = __builtin_amdgcn_rcpf(dnm.w + EPSC);

    // ---- semantic aggregation: 4 edges/iter, coalesced ----
    {
      float sm00 = 0.f, sm01 = 0.f, sm10 = 0.f, sm11 = 0.f;
      float sm20 = 0.f, sm21 = 0.f, sm30 = 0.f, sm31 = 0.f;
      int k = s;
      for (; k + 4 <= epd; k += 4) {
        const unsigned hv = ((const unsigned*)heb)[k * 16 + lane];
        const float4 ex = ((const float4*)expl)[k + q];
        const float h0 = bf2f((ushort_t)(hv & 0xffffu));
        const float h1 = bf2f((ushort_t)(hv >> 16));
        sm00 += ex.x * h0; sm01 += ex.x * h1;
        sm10 += ex.y * h0; sm11 += ex.y * h1;
        sm20 += ex.z * h0; sm21 += ex.z * h1;
        sm30 += ex.w * h0; sm31 += ex.w * h1;
      }
      if (k < epd) {
        const int ke = k + q;
        const int kl = (ke < epd) ? ke : (epd - 1);
        const float live = (ke < epd) ? 1.0f : 0.0f;
        const unsigned hv = ((const unsigned*)heb)[kl * 16 + l15];
        const float4 ex = ((const float4*)expl)[kl];
        const float h0 = bf2f((ushort_t)(hv & 0xffffu)) * live;
        const float h1 = bf2f((ushort_t)(hv >> 16)) * live;
        sm00 += ex.x * h0; sm01 += ex.x * h1;
        sm10 += ex.y * h0; sm11 += ex.y * h1;
        sm20 += ex.z * h0; sm21 += ex.z * h1;
        sm30 += ex.w * h0; sm31 += ex.w * h1;
      }
      // reduce across the 4 edge subgroups (lanes xor 16, 32)
      sm00 += __shfl_xor(sm00, 16); sm00 += __shfl_xor(sm00, 32);
      sm01 += __shfl_xor(sm01, 16); sm01 += __shfl_xor(sm01, 32);
      sm10 += __shfl_xor(sm10, 16); sm10 += __shfl_xor(sm10, 32);
      sm11 += __shfl_xor(sm11, 16); sm11 += __shfl_xor(sm11, 32);
      sm20 += __shfl_xor(sm20, 16); sm20 += __shfl_xor(sm20, 32);
      sm21 += __shfl_xor(sm21, 16); sm21 += __shfl_xor(sm21, 32);
      sm30 += __shfl_xor(sm30, 16); sm30 += __shfl_xor(sm30, 32);
      sm31 += __shfl_xor(sm31, 16); sm31 += __shfl_xor(sm31, 32);
      // lane (g=q, cp=l15) writes head q, channels 2cp, 2cp+1
      const float sa = (q & 2) ? ((q & 1) ? sm30 : sm20)
                               : ((q & 1) ? sm10 : sm00);
      const float sb = (q & 2) ? ((q & 1) ? sm31 : sm21)
                               : ((q & 1) ? sm11 : sm01);
      const float idn = (q & 2) ? ((q & 1) ? invden[3] : invden[2])
                                : ((q & 1) ? invden[1] : invden[0]);
      const unsigned pack = (unsigned)f2bfu(sa * idn) |
                            ((unsigned)f2bfu(sb * idn) << 16);
      ((unsigned*)hsem)[n * 64 + lane] = pack;
    }

    // ---- spatial mix + comb reductions, 16-edge MFMA chunks ----
    float cx0 = 0.f, cy0 = 0.f, cz0 = 0.f;   // comb col = l15
    float cx1 = 0.f, cy1 = 0.f, cz1 = 0.f;   // comb col = 16+l15

    for (int c0 = 0; c0 < deg; c0 += 16) {
      const int ra = c0 + l15;
      const int eA = s + ((ra < deg) ? ra : (deg - 1));
      const v8s hech = *(const v8s*)(heb + eA * 32 + q * 8);

      // y[h][nt] = (heb chunk) @ Wx_h  (raw bf16 A-operand)
      v4f y[4][2];
      #pragma unroll
      for (int h4 = 0; h4 < 4; ++h4) {
        #pragma unroll
        for (int nt = 0; nt < 2; ++nt) {
          v4f z = {0.f, 0.f, 0.f, 0.f};
          y[h4][nt] = __builtin_amdgcn_mfma_f32_16x16x32_bf16(
              hech, *(const v8s*)(bXl + (h4 * 2 + nt) * 512), z, 0, 0, 0);
        }
      }

      #pragma unroll
      for (int r = 0; r < 4; ++r) {
        const int rr = c0 + q * 4 + r;
        const int live = rr < deg;
        const int eR = s + (live ? rr : (deg - 1));
        const float lf = live ? 1.0f : 0.0f;
        const float4 ex4 = *(const float4*)(expl + eR * 4);
        const float at0 = ex4.x * invden[0] * lf;
        const float at1 = ex4.y * invden[1] * lf;
        const float at2 = ex4.z * invden[2] * lf;
        const float at3 = ex4.w * invden[3] * lf;
        const float p0 = at0 * y[0][0][r] + at1 * y[1][0][r] +
                         at2 * y[2][0][r] + at3 * y[3][0][r];
        const float p1 = at0 * y[0][1][r] + at1 * y[1][1][r] +
                         at2 * y[2][1][r] + at3 * y[3][1][r];
        const float4 dq = dirb[eR];
        const float m0 = tanhfast(p0);   // = 0 for pad rows (p = 0)
        const float m1 = tanhfast(p1);
        cx0 += dq.x * m0; cy0 += dq.y * m0; cz0 += dq.z * m0;
        cx1 += dq.x * m1; cy1 += dq.y * m1; cz1 += dq.z * m1;
      }
    }

    // reduce comb over the 4 q-groups
    cx0 += __shfl_xor(cx0, 16); cx0 += __shfl_xor(cx0, 32);
    cy0 += __shfl_xor(cy0, 16); cy0 += __shfl_xor(cy0, 32);
    cz0 += __shfl_xor(cz0, 16); cz0 += __shfl_xor(cz0, 32);
    cx1 += __shfl_xor(cx1, 16); cx1 += __shfl_xor(cx1, 32);
    cy1 += __shfl_xor(cy1, 16); cy1 += __shfl_xor(cy1, 32);
    cz1 += __shfl_xor(cz1, 16); cz1 += __shfl_xor(cz1, 32);

    const float cinv = __builtin_amdgcn_rcpf(fmaxf((float)deg, 1.0f));

    // norm2: lanes 0..31 write one coalesced row (col = lane)
    if (lane < 32) {
      const float mx = ((lane & 16) ? cx1 : cx0) * cinv;
      const float my = ((lane & 16) ? cy1 : cy0) * cinv;
      const float mz = ((lane & 16) ? cz1 : cz0) * cinv;
      norm2[n * 32 + lane] = mx * mx + my * my + mz * mz;
    }

    // dv = sum_c wv[c] * comb[c] * cinv   (identity)
    float tx = wv0 * cx0 + wv1 * cx1;
    float ty = wv0 * cy0 + wv1 * cy1;
    float tz = wv0 * cz0 + wv1 * cz1;
    tx += __shfl_xor(tx, 1); tx += __shfl_xor(tx, 2);
    tx += __shfl_xor(tx, 4); tx += __shfl_xor(tx, 8);
    ty += __shfl_xor(ty, 1); ty += __shfl_xor(ty, 2);
    ty += __shfl_xor(ty, 4); ty += __shfl_xor(ty, 8);
    tz += __shfl_xor(tz, 1); tz += __shfl_xor(tz, 2);
    tz += __shfl_xor(tz, 4); tz += __shfl_xor(tz, 8);
    if (lane == 0) {
      dv_mean[n * 3 + 0] = tx * cinv;
      dv_mean[n * 3 + 1] = ty * cinv;
      dv_mean[n * 3 + 2] = tz * cinv;
    }

    sC = sN; eC = eN;
  }
}

// ---------------------------------------------------------------------------
// C1 (MFMA): spatial MLP (post1/post2) + node1 -> nh bf16 [N,128]
// (best-measured: sW1t in LDS, grid 512)
// ---------------------------------------------------------------------------
#define W1S 232
__global__ __launch_bounds__(256) void node_c1_mfma(
    const ushort_t* __restrict__ h_bf, const ushort_t* __restrict__ hsem,
    const float* __restrict__ norm2,
    const float* __restrict__ W_post1, const float* __restrict__ b_post1,
    const float* __restrict__ W_post2, const float* __restrict__ b_post2,
    const float* __restrict__ W_node1, const float* __restrict__ b_node1,
    ushort_t* __restrict__ nh_out, int N)
{
  __shared__ ushort_t sW1t[128 * W1S];
  __shared__ ushort_t tp[4][16 * THS];

  const int tid = threadIdx.x;
  for (int idx = tid; idx < 224 * 128; idx += 256) {
    const int k = idx >> 7;
    const int c = idx & 127;
    sW1t[c * W1S + k] = f2bfu(W_node1[idx]);
  }
  __syncthreads();

  const int lane = tid & 63;
  const int w = tid >> 6;
  const int l15 = lane & 15;
  const int q = lane >> 4;

  v8s bp1[4];
  #pragma unroll
  for (int nt = 0; nt < 4; ++nt)
    #pragma unroll
    for (int j = 0; j < 8; ++j)
      bp1[nt][j] = f2bfs(W_post1[(q * 8 + j) * 64 + nt * 16 + l15]);
  v8s bp2[2][2];
  #pragma unroll
  for (int kc = 0; kc < 2; ++kc)
    #pragma unroll
    for (int nt = 0; nt < 2; ++nt)
      #pragma unroll
      for (int j = 0; j < 8; ++j)
        bp2[kc][nt][j] = f2bfs(W_post2[(kc * 32 + q * 8 + j) * 32 + nt * 16 + l15]);
  float bb1[4];
  #pragma unroll
  for (int nt = 0; nt < 4; ++nt) bb1[nt] = b_post1[nt * 16 + l15];
  float bb2[2];
  #pragma unroll
  for (int nt = 0; nt < 2; ++nt) bb2[nt] = b_post2[nt * 16 + l15];
  float b1[8];
  #pragma unroll
  for (int nt = 0; nt < 8; ++nt) b1[nt] = b_node1[nt * 16 + l15];

  const int gw = blockIdx.x * 4 + w;
  const int nwv = gridDim.x * 4;
  const int ntiles = (N + 15) >> 4;

  for (int t = gw; t < ntiles; t += nwv) {
    const int row = t * 16 + l15;
    const int rowL = (row < N) ? row : (N - 1);

    const float4 nA = *(const float4*)(norm2 + (size_t)rowL * 32 + q * 8);
    const float4 nB = *(const float4*)(norm2 + (size_t)rowL * 32 + q * 8 + 4);
    v8s a1;
    a1[0] = f2bfs(nA.x); a1[1] = f2bfs(nA.y);
    a1[2] = f2bfs(nA.z); a1[3] = f2bfs(nA.w);
    a1[4] = f2bfs(nB.x); a1[5] = f2bfs(nB.y);
    a1[6] = f2bfs(nB.z); a1[7] = f2bfs(nB.w);

    v4f p1[4];
    #pragma unroll
    for (int nt = 0; nt < 4; ++nt) {
      v4f a = {0.f, 0.f, 0.f, 0.f};
      p1[nt] = __builtin_amdgcn_mfma_f32_16x16x32_bf16(a1, bp1[nt], a, 0, 0, 0);
    }
    #pragma unroll
    for (int nt = 0; nt < 4; ++nt)
      #pragma unroll
      for (int r = 0; r < 4; ++r)
        tp[w][(q * 4 + r) * THS + nt * 16 + l15] =
            f2bfu(siluf(p1[nt][r] + bb1[nt]));
    __builtin_amdgcn_wave_barrier();

    v8s a2[2];
    a2[0] = *(const v8s*)&tp[w][l15 * THS + q * 8];
    a2[1] = *(const v8s*)&tp[w][l15 * THS + 32 + q * 8];

    v4f p2[2];
    #pragma unroll
    for (int nt = 0; nt < 2; ++nt) {
      v4f a = {0.f, 0.f, 0.f, 0.f};
      #pragma unroll
      for (int kc = 0; kc < 2; ++kc)
        a = __builtin_amdgcn_mfma_f32_16x16x32_bf16(a2[kc], bp2[kc][nt], a, 0, 0, 0);
      p2[nt] = a;
    }
    __builtin_amdgcn_wave_barrier();
    #pragma unroll
    for (int nt = 0; nt < 2; ++nt)
      #pragma unroll
      for (int r = 0; r < 4; ++r)
        tp[w][(q * 4 + r) * THS + nt * 16 + l15] =
            f2bfu(siluf(p2[nt][r] + bb2[nt]));
    __builtin_amdgcn_wave_barrier();

    v8s af[7];
    af[0] = *(const v8s*)(h_bf + (size_t)rowL * 64 + q * 8);
    af[1] = *(const v8s*)(h_bf + (size_t)rowL * 64 + 32 + q * 8);
    #pragma unroll
    for (int kc = 0; kc < 4; ++kc)
      af[2 + kc] = *(const v8s*)(hsem + (size_t)rowL * 128 + kc * 32 + q * 8);
    af[6] = *(const v8s*)&tp[w][l15 * THS + q * 8];

    v4f acc[8];
    #pragma unroll
    for (int nt = 0; nt < 8; ++nt) acc[nt] = (v4f){0.f, 0.f, 0.f, 0.f};
    #pragma unroll
    for (int kc = 0; kc < 7; ++kc) {
      #pragma unroll
      for (int nt = 0; nt < 8; ++nt) {
        const v8s bfrag =
            *(const v8s*)&sW1t[(nt * 16 + l15) * W1S + kc * 32 + q * 8];
        acc[nt] = __builtin_amdgcn_mfma_f32_16x16x32_bf16(af[kc], bfrag, acc[nt], 0, 0, 0);
      }
    }

    const int rowb = t * 16 + q * 4;
    #pragma unroll
    for (int nt = 0; nt < 8; ++nt) {
      #pragma unroll
      for (int r = 0; r < 4; ++r)
        if (rowb + r < N)
          nh_out[(size_t)(rowb + r) * 128 + nt * 16 + l15] =
              f2bfu(siluf(acc[nt][r] + b1[nt]));
    }
  }
}

// ---------------------------------------------------------------------------
// C2 (MFMA): node2 + vel1 + gate + v/x update (dv_mean precomputed)
// (best-measured: grid 512)
// ---------------------------------------------------------------------------
__global__ __launch_bounds__(256) void node_c2_mfma(
    const float* __restrict__ h, const float* __restrict__ x,
    const float* __restrict__ v, const ushort_t* __restrict__ nh,
    const float* __restrict__ dv_mean,
    const float* __restrict__ W_node2, const float* __restrict__ b_node2,
    const float* __restrict__ W_vel1, const float* __restrict__ b_vel1,
    const float* __restrict__ W_vel2,
    float* __restrict__ out, int N)
{
  __shared__ ushort_t sW2[16 * 64 * 8];
  __shared__ ushort_t sWv[4 * 64 * 8];
  __shared__ ushort_t tH[4][16 * THS];
  __shared__ float sg[4][16];

  const int tid = threadIdx.x;
  for (int idx = tid; idx < 16 * 64 * 8; idx += 256) {
    const int j = idx & 7;
    const int ln = (idx >> 3) & 63;
    const int f = idx >> 9;
    const int k = (f >> 2) * 32 + (ln >> 4) * 8 + j;
    const int col = (f & 3) * 16 + (ln & 15);
    sW2[idx] = f2bfu(W_node2[k * 64 + col]);
  }
  for (int idx = tid; idx < 4 * 64 * 8; idx += 256) {
    const int j = idx & 7;
    const int ln = (idx >> 3) & 63;
    const int f = idx >> 9;
    const int k = (f >> 1) * 32 + (ln >> 4) * 8 + j;
    const int col = (f & 1) * 16 + (ln & 15);
    sWv[idx] = f2bfu(W_vel1[k * 32 + col]);
  }
  __syncthreads();

  const int lane = tid & 63;
  const int w = tid >> 6;
  const int l15 = lane & 15;
  const int q = lane >> 4;

  const ushort_t* w2l = sW2 + lane * 8;
  const ushort_t* wvl = sWv + lane * 8;

  float b2[4];
  #pragma unroll
  for (int nt = 0; nt < 4; ++nt) b2[nt] = b_node2[nt * 16 + l15];
  float bv[2];
  #pragma unroll
  for (int nt = 0; nt < 2; ++nt) bv[nt] = b_vel1[nt * 16 + l15];
  float wv2[2];
  #pragma unroll
  for (int nt = 0; nt < 2; ++nt) wv2[nt] = W_vel2[nt * 16 + l15];

  const int gw = blockIdx.x * 4 + w;
  const int nwv = gridDim.x * 4;
  const int ntiles = (N + 15) >> 4;

  for (int t = gw; t < ntiles; t += nwv) {
    const int row = t * 16 + l15;
    const int rowL = (row < N) ? row : (N - 1);

    v8s af[4];
    #pragma unroll
    for (int kc = 0; kc < 4; ++kc)
      af[kc] = *(const v8s*)(nh + (size_t)rowL * 128 + kc * 32 + q * 8);

    v4f acc[4];
    #pragma unroll
    for (int nt = 0; nt < 4; ++nt) {
      v4f a = {0.f, 0.f, 0.f, 0.f};
      #pragma unroll
      for (int kc = 0; kc < 4; ++kc) {
        const v8s bfrag = *(const v8s*)(w2l + (kc * 4 + nt) * 512);
        a = __builtin_amdgcn_mfma_f32_16x16x32_bf16(af[kc], bfrag, a, 0, 0, 0);
      }
      acc[nt] = a;
    }

    const int rowb = t * 16 + q * 4;
    #pragma unroll
    for (int nt = 0; nt < 4; ++nt) {
      const int col = nt * 16 + l15;
      #pragma unroll
      for (int r = 0; r < 4; ++r) {
        const int n = rowb + r;
        if (n < N) {
          const float hu = h[(size_t)n * 64 + col] + siluf(acc[nt][r] + b2[nt]);
          out[(size_t)n * 64 + col] = hu;
          tH[w][(q * 4 + r) * THS + col] = f2bfu(hu);
        }
      }
    }
    __builtin_amdgcn_wave_barrier();

    v8s a2[2];
    a2[0] = *(const v8s*)&tH[w][l15 * THS + q * 8];
    a2[1] = *(const v8s*)&tH[w][l15 * THS + 32 + q * 8];
    v4f av[2];
    #pragma unroll
    for (int nt = 0; nt < 2; ++nt) {
      v4f a = {0.f, 0.f, 0.f, 0.f};
      #pragma unroll
      for (int kc = 0; kc < 2; ++kc) {
        const v8s bfrag = *(const v8s*)(wvl + (kc * 2 + nt) * 512);
        a = __builtin_amdgcn_mfma_f32_16x16x32_bf16(a2[kc], bfrag, a, 0, 0, 0);
      }
      av[nt] = a;
    }

    #pragma unroll
    for (int r = 0; r < 4; ++r) {
      float pr = siluf(av[0][r] + bv[0]) * wv2[0] +
                 siluf(av[1][r] + bv[1]) * wv2[1];
      pr += __shfl_xor(pr, 1);
      pr += __shfl_xor(pr, 2);
      pr += __shfl_xor(pr, 4);
      pr += __shfl_xor(pr, 8);
      if (l15 == 0)
        sg[w][q * 4 + r] = 2.0f * __builtin_amdgcn_rcpf(1.0f + __expf(-pr));
    }
    __builtin_amdgcn_wave_barrier();

    if (lane < 48) {
      const int rr = lane / 3;
      const int c = lane % 3;
      const int n = t * 16 + rr;
      if (n < N) {
        const float gate = sg[w][rr];
        const float dv = dv_mean[n * 3 + c];
        const float vu = gate * v[n * 3 + c] + dv;
        out[(size_t)N * 64 + (size_t)n * 3 + c] = x[n * 3 + c] + vu;
        out[(size_t)N * 64 + (size_t)N * 3 + (size_t)n * 3 + c] = vu;
      }
    }
    __builtin_amdgcn_wave_barrier();
  }
}

// ---------------------------------------------------------------------------
extern "C" void kernel_launch(void* const* d_in, const int* in_sizes, int n_in,
                              void* d_out, int out_size, void* d_ws, size_t ws_size,
                              hipStream_t stream) {
  const float* h   = (const float*)d_in[0];
  const float* x   = (const float*)d_in[1];
  const float* v   = (const float*)d_in[2];
  const int* idx_i = (const int*)d_in[3];
  const int* idx_j = (const int*)d_in[4];
  const float* W_edge_in  = (const float*)d_in[5];
  const float* b_edge_in  = (const float*)d_in[6];
  const float* W_edge_h   = (const float*)d_in[7];
  const float* b_edge_h   = (const float*)d_in[8];
  const float* W_edge_out = (const float*)d_in[9];
  const float* b_edge_out = (const float*)d_in[10];
  const float* W_att      = (const float*)d_in[11];
  const float* b_att      = (const float*)d_in[12];
  const float* W_x_mix    = (const float*)d_in[13];
  const float* W_node1    = (const float*)d_in[14];
  const float* b_node1    = (const float*)d_in[15];
  const float* W_node2    = (const float*)d_in[16];
  const float* b_node2    = (const float*)d_in[17];
  const float* W_post1    = (const float*)d_in[18];
  const float* b_post1    = (const float*)d_in[19];
  const float* W_post2    = (const float*)d_in[20];
  const float* b_post2    = (const float*)d_in[21];
  const float* W_vel1     = (const float*)d_in[22];
  const float* b_vel1     = (const float*)d_in[23];
  const float* W_vel2     = (const float*)d_in[24];
  const float* w_v_mix    = (const float*)d_in[25];

  const int E = in_sizes[3];
  const int N = in_sizes[0] / DA;

  float* ws = (float*)d_ws;
  size_t off = 0;
  float* denom    = ws + off; off += (size_t)N * 4;     // zeroed
  int*   deg      = (int*)(ws + off); off += (size_t)N; // zeroed
  const size_t zeroBytes = off * sizeof(float);
  int*   rowstart = (int*)(ws + off); off += (size_t)N + 4;
  int*   cursor   = (int*)(ws + off); off += (size_t)N;
  int*   tsum     = (int*)(ws + off); off += (size_t)SCAN_T;
  int2*  ijperm   = (int2*)(ws + off); off += (size_t)E * 2;
  float* expl     = ws + off; off += (size_t)E * 4;
  float* dirbR    = ws + off; off += (size_t)E * 4;
  float* hsemR    = ws + off; off += (size_t)N * 64;
  float* norm2    = ws + off; off += (size_t)N * 32;
  float* dv_mean  = ws + off; off += (size_t)N * 4;
  float* hbfR     = ws + off; off += (size_t)N * 32;
  float* fltR     = ws + off; off += (size_t)E * 16;    // nh
  float* hebR     = ws + off; off += (size_t)E * 16;

  ushort_t* h_bf = (ushort_t*)hbfR;
  ushort_t* hsem = (ushort_t*)hsemR;
  ushort_t* heb  = (ushort_t*)hebR;
  ushort_t* nh   = (ushort_t*)fltR;
  float4*   dirb = (float4*)dirbR;

  hipMemsetAsync(d_ws, 0, zeroBytes, stream);

  {
    const int n4 = (N * 64) / 4;
    cast_count<<<1024, 256, 0, stream>>>(h, h_bf, n4, idx_i, deg, E);
  }
  {
    const int C = (N + SCAN_T - 1) / SCAN_T;
    deg_tsum<<<SCAN_B, 256, 0, stream>>>(deg, tsum, N, C);
    scan_tsum<<<1, 256, 0, stream>>>(tsum);
    write_csr<<<SCAN_B, 256, 0, stream>>>(deg, tsum, rowstart, cursor, N, C);
  }
  bucket_edges<<<512, 256, 0, stream>>>(idx_i, idx_j, cursor, ijperm, E);
  edge_f12<<<1024, 256, 0, stream>>>(h_bf, x, ijperm,
                                     W_edge_in, b_edge_in, W_edge_h, b_edge_h,
                                     W_edge_out, b_edge_out, W_att, b_att,
                                     dirb, heb, expl, denom, E);
  node_fused<<<2048, 256, 0, stream>>>(rowstart, heb, expl, denom, dirb,
                                       W_x_mix, w_v_mix, hsem, norm2,
                                       dv_mean, N);
  node_c1_mfma<<<512, 256, 0, stream>>>(
      h_bf, hsem, norm2, W_post1, b_post1, W_post2, b_post2,
      W_node1, b_node1, nh, N);
  node_c2_mfma<<<512, 256, 0, stream>>>(
      h, x, v, nh, dv_mean, W_node2, b_node2, W_vel1, b_vel1, W_vel2,
      (float*)d_out, N);
}